// Round 3
// baseline (76.213 us; speedup 1.0000x reference)
//
#include <hip/hip_runtime.h>

// HexaToParallelogram: out[b, cell] = idx[cell] >= 0 ? hexa[b, idx[cell]] : 0.0f
// B = 32768, NP = 1039 hex pixels/row, P = 31*39 = 1209 dense cells/row.
// ~295 MB compulsory traffic; fills demonstrate ~7.1 TB/s on these buffers
// -> ~42 us floor.
//
// R2: stride-1 scalar ownership. Consecutive lanes own consecutive output
// cells -> gather reads are perfectly coalesced (idx is monotone within hex
// row-runs), gidx reads are stride-1 and L1-resident (4.8 KB table, no LDS,
// no syncthreads), stores are stride-1 dword. Branchless masking via
// max(id,0) + select.

constexpr int NP = 1039;   // NUM_PIXELS
constexpr int P  = 1209;   // (2*q_max+1) * (2*r_max+1) = 31 * 39

__global__ void hexa_gather_s1(const float* __restrict__ hexa,
                               const int* __restrict__ gidx,
                               float* __restrict__ out,
                               int n) {
  const int stride = gridDim.x * blockDim.x;
  for (int i = blockIdx.x * blockDim.x + threadIdx.x; i < n; i += stride) {
    int b = i / P;                    // constant divisor -> magic-mul
    int p = i - b * P;
    int id = gidx[p];                 // coalesced, L1-hot (4.8 KB table)
    int safe = id & ~(id >> 31);      // max(id, 0), branchless
    float v = hexa[(size_t)b * NP + safe];  // coalesced gather
    out[i] = (id >= 0) ? v : 0.0f;    // cndmask
  }
}

// Safety net: runtime-P path (same structure).
__global__ void hexa_gather_rt(const float* __restrict__ hexa,
                               const int* __restrict__ gidx,
                               float* __restrict__ out,
                               int n, int Prt) {
  const int stride = gridDim.x * blockDim.x;
  for (int i = blockIdx.x * blockDim.x + threadIdx.x; i < n; i += stride) {
    int b = i / Prt;
    int p = i - b * Prt;
    int id = gidx[p];
    int safe = id & ~(id >> 31);
    float v = hexa[(size_t)b * NP + safe];
    out[i] = (id >= 0) ? v : 0.0f;
  }
}

extern "C" void kernel_launch(void* const* d_in, const int* in_sizes, int n_in,
                              void* d_out, int out_size, void* d_ws, size_t ws_size,
                              hipStream_t stream) {
  const float* hexa = (const float*)d_in[0];
  const int*   gidx = (const int*)d_in[1];
  const int block = 256;

  int grid = (out_size + block - 1) / block;
  if (grid > 2048) grid = 2048;   // grid-stride; 8 blocks/CU, full occupancy

  if (in_sizes[1] == P) {
    hexa_gather_s1<<<grid, block, 0, stream>>>(hexa, gidx, (float*)d_out, out_size);
  } else {
    hexa_gather_rt<<<grid, block, 0, stream>>>(hexa, gidx, (float*)d_out,
                                               out_size, in_sizes[1]);
  }
}